// Round 1
// baseline (3052.720 us; speedup 1.0000x reference)
//
#include <hip/hip_runtime.h>
#include <cstdint>
#include <cstddef>

// Problem constants (match reference)
#define HIDDEN   2048
#define EINTER   1024
#define NEXP     8
#define VOCAB_SZ 100000
#define TOK_PER_EXP (VOCAB_SZ / NEXP)   // 12500

// GEMM tiling
#define TM 64
#define TN 64
#define TK 16

__device__ __forceinline__ int expert_of(int id) {
  id = id < 0 ? 0 : (id > VOCAB_SZ - 1 ? VOCAB_SZ - 1 : id);
  int e = id / TOK_PER_EXP;
  return e > NEXP - 1 ? NEXP - 1 : e;
}

// ---------------- routing ----------------
__global__ void count_kernel(const int* __restrict__ tok_ids, int* __restrict__ counts, int T) {
  int t = blockIdx.x * blockDim.x + threadIdx.x;
  if (t < T) atomicAdd(&counts[expert_of(tok_ids[t])], 1);
}

__global__ void scan_kernel(const int* __restrict__ counts, int* __restrict__ offsets,
                            int* __restrict__ cursors) {
  if (threadIdx.x == 0) {
    int s = 0;
    for (int e = 0; e < NEXP; ++e) { offsets[e] = s; cursors[e] = s; s += counts[e]; }
  }
}

__global__ void scatter_kernel(const int* __restrict__ tok_ids, int* __restrict__ cursors,
                               int* __restrict__ tok_list, int T) {
  int t = blockIdx.x * blockDim.x + threadIdx.x;
  if (t < T) {
    int e = expert_of(tok_ids[t]);
    int pos = atomicAdd(&cursors[e], 1);
    tok_list[pos] = t;  // order within expert is arbitrary; per-token math is unaffected
  }
}

// ---------------- gate/up GEMM + silu*mul ----------------
// grid: (EINTER/TN, ceil(T/TM), NEXP), block 256
__global__ __launch_bounds__(256, 2) void gate_up_kernel(
    const float* __restrict__ x,
    const float* __restrict__ G,
    const float* __restrict__ U,
    const int* __restrict__ counts,
    const int* __restrict__ offsets,
    const int* __restrict__ tok_list,
    float* __restrict__ act) {
  __shared__ __align__(16) float Xs[TK][TM + 4];  // +4 keeps b128 alignment, 2-way-max bank alias
  __shared__ __align__(16) float Gs[TK][TN];
  __shared__ __align__(16) float Us[TK][TN];
  __shared__ int toks[TM];

  const int e    = blockIdx.z;
  const int cnt  = counts[e];
  const int row0 = blockIdx.y * TM;
  if (row0 >= cnt) return;   // uniform per block
  const int off = offsets[e];
  const int i0  = blockIdx.x * TN;

  const int tid = threadIdx.x;
  if (tid < TM) {
    int r = row0 + tid;
    toks[tid] = tok_list[off + (r < cnt ? r : 0)];  // clamp: safe loads, masked stores
  }
  __syncthreads();

  const float* __restrict__ Ge = G + (size_t)e * HIDDEN * EINTER + i0;
  const float* __restrict__ Ue = U + (size_t)e * HIDDEN * EINTER + i0;

  const int kk_ld = tid & 15;   // X staging
  const int r_ld  = tid >> 4;
  const int i_ld  = tid & 63;   // G/U staging
  const int k_ld  = tid >> 6;
  const int tx = tid & 15;      // compute micro-tile
  const int ty = tid >> 4;

  float ag[4][4] = {{0.f}};
  float au[4][4] = {{0.f}};

  for (int k0 = 0; k0 < HIDDEN; k0 += TK) {
#pragma unroll
    for (int rr = 0; rr < 4; ++rr) {
      int r = r_ld + rr * 16;
      Xs[kk_ld][r] = x[(size_t)toks[r] * HIDDEN + k0 + kk_ld];
    }
#pragma unroll
    for (int kk = 0; kk < 4; ++kk) {
      int k = k_ld + kk * 4;
      Gs[k][i_ld] = Ge[(size_t)(k0 + k) * EINTER + i_ld];
      Us[k][i_ld] = Ue[(size_t)(k0 + k) * EINTER + i_ld];
    }
    __syncthreads();
#pragma unroll
    for (int kk = 0; kk < TK; ++kk) {
      float4 a  = *(const float4*)&Xs[kk][ty * 4];
      float4 bg = *(const float4*)&Gs[kk][tx * 4];
      float4 bu = *(const float4*)&Us[kk][tx * 4];
      const float av[4]  = {a.x, a.y, a.z, a.w};
      const float bgv[4] = {bg.x, bg.y, bg.z, bg.w};
      const float buv[4] = {bu.x, bu.y, bu.z, bu.w};
#pragma unroll
      for (int i = 0; i < 4; ++i)
#pragma unroll
        for (int j = 0; j < 4; ++j) {
          ag[i][j] = fmaf(av[i], bgv[j], ag[i][j]);
          au[i][j] = fmaf(av[i], buv[j], au[i][j]);
        }
    }
    __syncthreads();
  }

#pragma unroll
  for (int i = 0; i < 4; ++i) {
    int r = row0 + ty * 4 + i;
    if (r < cnt) {
      float4 o;
      float* op = (float*)&o;
#pragma unroll
      for (int j = 0; j < 4; ++j) {
        float g = ag[i][j];
        float u = au[i][j];
        op[j] = (g / (1.0f + expf(-g))) * u;   // silu(g)*u
      }
      *(float4*)&act[(size_t)(off + r) * EINTER + i0 + tx * 4] = o;
    }
  }
}

// ---------------- down GEMM, scatter to out ----------------
// grid: (HIDDEN/TN, ceil(T/TM), NEXP), block 256
__global__ __launch_bounds__(256, 2) void down_kernel(
    const float* __restrict__ act,
    const float* __restrict__ D,
    const int* __restrict__ counts,
    const int* __restrict__ offsets,
    const int* __restrict__ tok_list,
    float* __restrict__ out) {
  __shared__ __align__(16) float As[TK][TM + 4];
  __shared__ __align__(16) float Ds[TK][TN];
  __shared__ int toks[TM];

  const int e    = blockIdx.z;
  const int cnt  = counts[e];
  const int row0 = blockIdx.y * TM;
  if (row0 >= cnt) return;
  const int off = offsets[e];
  const int j0  = blockIdx.x * TN;

  const int tid = threadIdx.x;
  if (tid < TM) {
    int r = row0 + tid;
    toks[tid] = tok_list[off + (r < cnt ? r : 0)];
  }

  const float* __restrict__ De = D + (size_t)e * EINTER * HIDDEN + j0;

  const int kk_ld = tid & 15;
  const int r_ld  = tid >> 4;
  const int i_ld  = tid & 63;
  const int k_ld  = tid >> 6;
  const int tx = tid & 15;
  const int ty = tid >> 4;

  float acc[4][4] = {{0.f}};

  for (int k0 = 0; k0 < EINTER; k0 += TK) {
#pragma unroll
    for (int rr = 0; rr < 4; ++rr) {
      int r = r_ld + rr * 16;
      int grow = row0 + r;
      As[kk_ld][r] = act[(size_t)(off + (grow < cnt ? grow : 0)) * EINTER + k0 + kk_ld];
    }
#pragma unroll
    for (int kk = 0; kk < 4; ++kk) {
      int k = k_ld + kk * 4;
      Ds[k][i_ld] = De[(size_t)(k0 + k) * HIDDEN + i_ld];
    }
    __syncthreads();   // also covers toks[] for the epilogue
#pragma unroll
    for (int kk = 0; kk < TK; ++kk) {
      float4 a = *(const float4*)&As[kk][ty * 4];
      float4 b = *(const float4*)&Ds[kk][tx * 4];
      const float av[4] = {a.x, a.y, a.z, a.w};
      const float bv[4] = {b.x, b.y, b.z, b.w};
#pragma unroll
      for (int i = 0; i < 4; ++i)
#pragma unroll
        for (int j = 0; j < 4; ++j)
          acc[i][j] = fmaf(av[i], bv[j], acc[i][j]);
    }
    __syncthreads();
  }

#pragma unroll
  for (int i = 0; i < 4; ++i) {
    int r = row0 + ty * 4 + i;
    if (r < cnt) {
      float4 o = {acc[i][0], acc[i][1], acc[i][2], acc[i][3]};
      *(float4*)&out[(size_t)toks[ty * 4 + i] * HIDDEN + j0 + tx * 4] = o;
    }
  }
}

// ---------------- launch ----------------
extern "C" void kernel_launch(void* const* d_in, const int* in_sizes, int n_in,
                              void* d_out, int out_size, void* d_ws, size_t ws_size,
                              hipStream_t stream) {
  const float* x       = (const float*)d_in[0];
  const int*   tok_ids = (const int*)d_in[1];   // per harness contract: integer -> const int*
  const float* G       = (const float*)d_in[2];
  const float* U       = (const float*)d_in[3];
  const float* D       = (const float*)d_in[4];
  float* out = (float*)d_out;

  const int T = in_sizes[0] / HIDDEN;  // 16384

  // ws layout: [counts(8) | offsets(8) | cursors(8) | tok_list(T)] pad256 [act: T*EINTER f32 ~67MB]
  int* counts   = (int*)d_ws;
  int* offsets  = counts + NEXP;
  int* cursors  = offsets + NEXP;
  int* tok_list = cursors + NEXP;
  size_t hdr_bytes = (((size_t)(3 * NEXP + T) * sizeof(int)) + 255) & ~(size_t)255;
  float* act = (float*)((char*)d_ws + hdr_bytes);

  hipMemsetAsync(counts, 0, NEXP * sizeof(int), stream);  // ws is poisoned 0xAA each call
  count_kernel<<<(T + 255) / 256, 256, 0, stream>>>(tok_ids, counts, T);
  scan_kernel<<<1, 64, 0, stream>>>(counts, offsets, cursors);
  scatter_kernel<<<(T + 255) / 256, 256, 0, stream>>>(tok_ids, cursors, tok_list, T);

  dim3 g1(EINTER / TN, (T + TM - 1) / TM, NEXP);
  gate_up_kernel<<<g1, 256, 0, stream>>>(x, G, U, counts, offsets, tok_list, act);

  dim3 g2(HIDDEN / TN, (T + TM - 1) / TM, NEXP);
  down_kernel<<<g2, 256, 0, stream>>>(act, D, counts, offsets, tok_list, out);
}

// Round 2
// 855.528 us; speedup vs baseline: 3.5682x; 3.5682x over previous
//
#include <hip/hip_runtime.h>
#include <hip/hip_bf16.h>
#include <cstdint>
#include <cstddef>

#define HIDDEN   2048
#define EINTER   1024
#define NEXP     8
#define VOCAB_SZ 100000
#define TOK_PER_EXP (VOCAB_SZ / NEXP)   // 12500

typedef unsigned short u16;
typedef __attribute__((ext_vector_type(8))) short short8;   // 8 bf16 in 4 VGPRs
typedef __attribute__((ext_vector_type(4))) float floatx4;  // MFMA C/D

__device__ __forceinline__ int expert_of(int id) {
  id = id < 0 ? 0 : (id > VOCAB_SZ - 1 ? VOCAB_SZ - 1 : id);
  int e = id / TOK_PER_EXP;
  return e > NEXP - 1 ? NEXP - 1 : e;
}

// ---------------- routing ----------------
__global__ void count_kernel(const int* __restrict__ tok_ids, int* __restrict__ counts, int T) {
  int t = blockIdx.x * blockDim.x + threadIdx.x;
  if (t < T) atomicAdd(&counts[expert_of(tok_ids[t])], 1);
}

__global__ void scan_kernel(const int* __restrict__ counts, int* __restrict__ offsets,
                            int* __restrict__ cursors) {
  if (threadIdx.x == 0) {
    int s = 0;
    for (int e = 0; e < NEXP; ++e) { offsets[e] = s; cursors[e] = s; s += counts[e]; }
  }
}

__global__ void scatter_kernel(const int* __restrict__ tok_ids, int* __restrict__ cursors,
                               int* __restrict__ tok_list, int T) {
  int t = blockIdx.x * blockDim.x + threadIdx.x;
  if (t < T) {
    int e = expert_of(tok_ids[t]);
    int pos = atomicAdd(&cursors[e], 1);
    tok_list[pos] = t;
  }
}

// ---------------- bf16 pre-pass ----------------
// gather x rows into expert-compact order, fp32 -> bf16. one block per compact row.
__global__ void gather_x_kernel(const float* __restrict__ x, const int* __restrict__ tok_list,
                                u16* __restrict__ xp) {
  const int row = blockIdx.x;
  const int tok = tok_list[row];
  const float* src = x + (size_t)tok * HIDDEN;
  u16* dst = xp + (size_t)row * HIDDEN;
  const int k = threadIdx.x * 8;           // 256 threads * 8 = 2048
  float4 a = *(const float4*)(src + k);
  float4 b = *(const float4*)(src + k + 4);
  union { uint4 u; u16 s[8]; } pk;
  const float f[8] = {a.x, a.y, a.z, a.w, b.x, b.y, b.z, b.w};
#pragma unroll
  for (int i = 0; i < 8; ++i) {
    __hip_bfloat16 h = __float2bfloat16(f[i]);
    pk.s[i] = *reinterpret_cast<u16*>(&h);
  }
  *(uint4*)(dst + k) = pk.u;
}

// transpose+convert: in fp32 [R][C] (per batch) -> out bf16 [C][R]. grid (C/32, R/32, batches)
__global__ void transpose_cvt_kernel(const float* __restrict__ in, u16* __restrict__ outp,
                                     int R, int C) {
  __shared__ float ts[32][33];
  const size_t bo = (size_t)blockIdx.z * R * C;
  const int c0 = blockIdx.x * 32, r0 = blockIdx.y * 32;
  const int tc = threadIdx.x & 31, tr = threadIdx.x >> 5;   // tr 0..7
#pragma unroll
  for (int i = 0; i < 4; ++i) {
    int r = tr + i * 8;
    ts[r][tc] = in[bo + (size_t)(r0 + r) * C + c0 + tc];
  }
  __syncthreads();
#pragma unroll
  for (int i = 0; i < 4; ++i) {
    int c = tr + i * 8;
    __hip_bfloat16 h = __float2bfloat16(ts[tc][c]);
    outp[bo + (size_t)(c0 + c) * R + r0 + tc] = *reinterpret_cast<u16*>(&h);
  }
}

// ---------------- gate/up MFMA GEMM + silu*mul -> act (bf16) ----------------
// tile: 128 rows x 64 cols (per G and U), BK=64. grid (EINTER/64, ceil(T/128), NEXP), 256 thr.
__global__ __launch_bounds__(256, 2) void gate_up_mfma(
    const u16* __restrict__ xp,    // [T][HIDDEN] bf16, expert-compact rows
    const u16* __restrict__ Gt,    // [E][EINTER][HIDDEN] bf16 (n-major)
    const u16* __restrict__ Ut,
    const int* __restrict__ counts,
    const int* __restrict__ offsets,
    u16* __restrict__ act) {       // [T][EINTER] bf16, compact rows
  __shared__ __align__(16) u16 As[128][72];
  __shared__ __align__(16) u16 Bg[64][72];
  __shared__ __align__(16) u16 Bu[64][72];

  const int e = blockIdx.z;
  const int cnt = counts[e];
  const int row0 = blockIdx.y * 128;
  if (row0 >= cnt) return;
  const int off = offsets[e];
  const int i0 = blockIdx.x * 64;

  const int tid  = threadIdx.x;
  const int lane = tid & 63;
  const int wave = tid >> 6;
  const int quad = lane >> 4;
  const int l16  = lane & 15;

  const int arow = tid >> 3;   // 0..31 (+32*it)
  const int ach  = tid & 7;

  const int wrow = (wave & 1) * 64;   // wave tile: 64 rows x 32 cols
  const int wcol = (wave >> 1) * 32;

  floatx4 accg[4][2], accu[4][2];
#pragma unroll
  for (int mf = 0; mf < 4; ++mf)
#pragma unroll
    for (int nf = 0; nf < 2; ++nf) {
      floatx4 z = {0.f, 0.f, 0.f, 0.f};
      accg[mf][nf] = z; accu[mf][nf] = z;
    }

  const u16* xbase = xp + (size_t)off * HIDDEN;
  const u16* gbase = Gt + ((size_t)e * EINTER + i0) * HIDDEN;
  const u16* ubase = Ut + ((size_t)e * EINTER + i0) * HIDDEN;

  for (int k0 = 0; k0 < HIDDEN; k0 += 64) {
#pragma unroll
    for (int it = 0; it < 4; ++it) {
      int r = arow + it * 32;
      int rg = row0 + r; rg = rg < cnt ? rg : cnt - 1;
      *(uint4*)&As[r][ach * 8] = *(const uint4*)(xbase + (size_t)rg * HIDDEN + k0 + ach * 8);
    }
#pragma unroll
    for (int it = 0; it < 2; ++it) {
      int n = arow + it * 32;
      *(uint4*)&Bg[n][ach * 8] = *(const uint4*)(gbase + (size_t)n * HIDDEN + k0 + ach * 8);
      *(uint4*)&Bu[n][ach * 8] = *(const uint4*)(ubase + (size_t)n * HIDDEN + k0 + ach * 8);
    }
    __syncthreads();
#pragma unroll
    for (int s = 0; s < 2; ++s) {
      short8 af[4], bgf[2], buf2[2];
#pragma unroll
      for (int mf = 0; mf < 4; ++mf)
        af[mf] = *(const short8*)&As[wrow + mf * 16 + l16][(s * 4 + quad) * 8];
#pragma unroll
      for (int nf = 0; nf < 2; ++nf) {
        bgf[nf]  = *(const short8*)&Bg[wcol + nf * 16 + l16][(s * 4 + quad) * 8];
        buf2[nf] = *(const short8*)&Bu[wcol + nf * 16 + l16][(s * 4 + quad) * 8];
      }
#pragma unroll
      for (int mf = 0; mf < 4; ++mf)
#pragma unroll
        for (int nf = 0; nf < 2; ++nf) {
          accg[mf][nf] = __builtin_amdgcn_mfma_f32_16x16x32_bf16(af[mf], bgf[nf],  accg[mf][nf], 0, 0, 0);
          accu[mf][nf] = __builtin_amdgcn_mfma_f32_16x16x32_bf16(af[mf], buf2[nf], accu[mf][nf], 0, 0, 0);
        }
    }
    __syncthreads();
  }

  // epilogue: silu(g)*u -> bf16 act. C/D layout: col=lane&15, row=quad*4+reg
#pragma unroll
  for (int mf = 0; mf < 4; ++mf)
#pragma unroll
    for (int nf = 0; nf < 2; ++nf)
#pragma unroll
      for (int rg = 0; rg < 4; ++rg) {
        int r = wrow + mf * 16 + quad * 4 + rg;
        if (row0 + r < cnt) {
          float g = accg[mf][nf][rg];
          float u = accu[mf][nf][rg];
          float y = (g / (1.f + __expf(-g))) * u;
          __hip_bfloat16 h = __float2bfloat16(y);
          act[((size_t)(off + row0 + r)) * EINTER + i0 + wcol + nf * 16 + l16] =
              *reinterpret_cast<u16*>(&h);
        }
      }
}

// ---------------- down MFMA GEMM, scatter fp32 to out ----------------
// tile: 128 rows x 128 cols, BK=64. grid (HIDDEN/128, ceil(T/128), NEXP), 256 thr.
__global__ __launch_bounds__(256, 2) void down_mfma(
    const u16* __restrict__ act,   // [T][EINTER] bf16 compact
    const u16* __restrict__ Dt,    // [E][HIDDEN][EINTER] bf16 (n-major)
    const int* __restrict__ counts,
    const int* __restrict__ offsets,
    const int* __restrict__ tok_list,
    float* __restrict__ out) {
  __shared__ __align__(16) u16 As[128][72];
  __shared__ __align__(16) u16 Bs[128][72];
  __shared__ int toks[128];

  const int e = blockIdx.z;
  const int cnt = counts[e];
  const int row0 = blockIdx.y * 128;
  if (row0 >= cnt) return;
  const int off = offsets[e];
  const int j0 = blockIdx.x * 128;

  const int tid  = threadIdx.x;
  const int lane = tid & 63;
  const int wave = tid >> 6;
  const int quad = lane >> 4;
  const int l16  = lane & 15;

  const int arow = tid >> 3;
  const int ach  = tid & 7;

  const int wrow = (wave & 1) * 64;   // wave tile: 64 x 64
  const int wcol = (wave >> 1) * 64;

  if (tid < 128) {
    int r = row0 + tid;
    toks[tid] = tok_list[off + (r < cnt ? r : cnt - 1)];
  }

  floatx4 acc[4][4];
#pragma unroll
  for (int mf = 0; mf < 4; ++mf)
#pragma unroll
    for (int nf = 0; nf < 4; ++nf) {
      floatx4 z = {0.f, 0.f, 0.f, 0.f};
      acc[mf][nf] = z;
    }

  const u16* abase = act + (size_t)off * EINTER;
  const u16* dbase = Dt + ((size_t)e * HIDDEN + j0) * EINTER;

  for (int k0 = 0; k0 < EINTER; k0 += 64) {
#pragma unroll
    for (int it = 0; it < 4; ++it) {
      int r = arow + it * 32;
      int rg = row0 + r; rg = rg < cnt ? rg : cnt - 1;
      *(uint4*)&As[r][ach * 8] = *(const uint4*)(abase + (size_t)rg * EINTER + k0 + ach * 8);
    }
#pragma unroll
    for (int it = 0; it < 4; ++it) {
      int n = arow + it * 32;
      *(uint4*)&Bs[n][ach * 8] = *(const uint4*)(dbase + (size_t)n * EINTER + k0 + ach * 8);
    }
    __syncthreads();
#pragma unroll
    for (int s = 0; s < 2; ++s) {
      short8 af[4], bf[4];
#pragma unroll
      for (int mf = 0; mf < 4; ++mf)
        af[mf] = *(const short8*)&As[wrow + mf * 16 + l16][(s * 4 + quad) * 8];
#pragma unroll
      for (int nf = 0; nf < 4; ++nf)
        bf[nf] = *(const short8*)&Bs[wcol + nf * 16 + l16][(s * 4 + quad) * 8];
#pragma unroll
      for (int mf = 0; mf < 4; ++mf)
#pragma unroll
        for (int nf = 0; nf < 4; ++nf)
          acc[mf][nf] = __builtin_amdgcn_mfma_f32_16x16x32_bf16(af[mf], bf[nf], acc[mf][nf], 0, 0, 0);
    }
    __syncthreads();
  }

#pragma unroll
  for (int mf = 0; mf < 4; ++mf)
#pragma unroll
    for (int nf = 0; nf < 4; ++nf)
#pragma unroll
      for (int rg = 0; rg < 4; ++rg) {
        int r = wrow + mf * 16 + quad * 4 + rg;
        if (row0 + r < cnt)
          out[(size_t)toks[r] * HIDDEN + j0 + wcol + nf * 16 + l16] = acc[mf][nf][rg];
      }
}

// ---------------- fp32 fallback GEMMs (round-1, known-correct) ----------------
#define TM 64
#define TN 64
#define TK 16

__global__ __launch_bounds__(256, 2) void gate_up_fp32(
    const float* __restrict__ x, const float* __restrict__ G, const float* __restrict__ U,
    const int* __restrict__ counts, const int* __restrict__ offsets,
    const int* __restrict__ tok_list, float* __restrict__ act) {
  __shared__ __align__(16) float Xs[TK][TM + 4];
  __shared__ __align__(16) float Gs[TK][TN];
  __shared__ __align__(16) float Us[TK][TN];
  __shared__ int toks[TM];
  const int e = blockIdx.z, cnt = counts[e], row0 = blockIdx.y * TM;
  if (row0 >= cnt) return;
  const int off = offsets[e], i0 = blockIdx.x * TN, tid = threadIdx.x;
  if (tid < TM) { int r = row0 + tid; toks[tid] = tok_list[off + (r < cnt ? r : 0)]; }
  __syncthreads();
  const float* Ge = G + (size_t)e * HIDDEN * EINTER + i0;
  const float* Ue = U + (size_t)e * HIDDEN * EINTER + i0;
  const int kk_ld = tid & 15, r_ld = tid >> 4, i_ld = tid & 63, k_ld = tid >> 6;
  const int tx = tid & 15, ty = tid >> 4;
  float ag[4][4] = {{0.f}}, au[4][4] = {{0.f}};
  for (int k0 = 0; k0 < HIDDEN; k0 += TK) {
#pragma unroll
    for (int rr = 0; rr < 4; ++rr) {
      int r = r_ld + rr * 16;
      Xs[kk_ld][r] = x[(size_t)toks[r] * HIDDEN + k0 + kk_ld];
    }
#pragma unroll
    for (int kk = 0; kk < 4; ++kk) {
      int k = k_ld + kk * 4;
      Gs[k][i_ld] = Ge[(size_t)(k0 + k) * EINTER + i_ld];
      Us[k][i_ld] = Ue[(size_t)(k0 + k) * EINTER + i_ld];
    }
    __syncthreads();
#pragma unroll
    for (int kk = 0; kk < TK; ++kk) {
      float4 a = *(const float4*)&Xs[kk][ty * 4];
      float4 bg = *(const float4*)&Gs[kk][tx * 4];
      float4 bu = *(const float4*)&Us[kk][tx * 4];
      const float av[4] = {a.x, a.y, a.z, a.w}, bgv[4] = {bg.x, bg.y, bg.z, bg.w},
                  buv[4] = {bu.x, bu.y, bu.z, bu.w};
#pragma unroll
      for (int i = 0; i < 4; ++i)
#pragma unroll
        for (int j = 0; j < 4; ++j) {
          ag[i][j] = fmaf(av[i], bgv[j], ag[i][j]);
          au[i][j] = fmaf(av[i], buv[j], au[i][j]);
        }
    }
    __syncthreads();
  }
#pragma unroll
  for (int i = 0; i < 4; ++i) {
    int r = row0 + ty * 4 + i;
    if (r < cnt) {
      float4 o; float* op = (float*)&o;
#pragma unroll
      for (int j = 0; j < 4; ++j) {
        float g = ag[i][j], u = au[i][j];
        op[j] = (g / (1.0f + expf(-g))) * u;
      }
      *(float4*)&act[(size_t)(off + r) * EINTER + i0 + tx * 4] = o;
    }
  }
}

__global__ __launch_bounds__(256, 2) void down_fp32(
    const float* __restrict__ act, const float* __restrict__ D,
    const int* __restrict__ counts, const int* __restrict__ offsets,
    const int* __restrict__ tok_list, float* __restrict__ out) {
  __shared__ __align__(16) float As[TK][TM + 4];
  __shared__ __align__(16) float Ds[TK][TN];
  __shared__ int toks[TM];
  const int e = blockIdx.z, cnt = counts[e], row0 = blockIdx.y * TM;
  if (row0 >= cnt) return;
  const int off = offsets[e], j0 = blockIdx.x * TN, tid = threadIdx.x;
  if (tid < TM) { int r = row0 + tid; toks[tid] = tok_list[off + (r < cnt ? r : 0)]; }
  const float* De = D + (size_t)e * EINTER * HIDDEN + j0;
  const int kk_ld = tid & 15, r_ld = tid >> 4, i_ld = tid & 63, k_ld = tid >> 6;
  const int tx = tid & 15, ty = tid >> 4;
  float acc[4][4] = {{0.f}};
  for (int k0 = 0; k0 < EINTER; k0 += TK) {
#pragma unroll
    for (int rr = 0; rr < 4; ++rr) {
      int r = r_ld + rr * 16;
      int grow = row0 + r;
      As[kk_ld][r] = act[(size_t)(off + (grow < cnt ? grow : 0)) * EINTER + k0 + kk_ld];
    }
#pragma unroll
    for (int kk = 0; kk < 4; ++kk) {
      int k = k_ld + kk * 4;
      Ds[k][i_ld] = De[(size_t)(k0 + k) * HIDDEN + i_ld];
    }
    __syncthreads();
#pragma unroll
    for (int kk = 0; kk < TK; ++kk) {
      float4 a = *(const float4*)&As[kk][ty * 4];
      float4 b = *(const float4*)&Ds[kk][tx * 4];
      const float av[4] = {a.x, a.y, a.z, a.w}, bv[4] = {b.x, b.y, b.z, b.w};
#pragma unroll
      for (int i = 0; i < 4; ++i)
#pragma unroll
        for (int j = 0; j < 4; ++j)
          acc[i][j] = fmaf(av[i], bv[j], acc[i][j]);
    }
    __syncthreads();
  }
#pragma unroll
  for (int i = 0; i < 4; ++i) {
    int r = row0 + ty * 4 + i;
    if (r < cnt) {
      float4 o = {acc[i][0], acc[i][1], acc[i][2], acc[i][3]};
      *(float4*)&out[(size_t)toks[ty * 4 + i] * HIDDEN + j0 + tx * 4] = o;
    }
  }
}

// ---------------- launch ----------------
extern "C" void kernel_launch(void* const* d_in, const int* in_sizes, int n_in,
                              void* d_out, int out_size, void* d_ws, size_t ws_size,
                              hipStream_t stream) {
  const float* x       = (const float*)d_in[0];
  const int*   tok_ids = (const int*)d_in[1];
  const float* G       = (const float*)d_in[2];
  const float* U       = (const float*)d_in[3];
  const float* D       = (const float*)d_in[4];
  float* out = (float*)d_out;

  const int T = in_sizes[0] / HIDDEN;  // 16384

  // header: counts(8) | offsets(8) | cursors(8) | tok_list(T)
  int* counts   = (int*)d_ws;
  int* offsets  = counts + NEXP;
  int* cursors  = offsets + NEXP;
  int* tok_list = cursors + NEXP;
  size_t hdr_bytes = (((size_t)(3 * NEXP + T) * sizeof(int)) + 255) & ~(size_t)255;

  hipMemsetAsync(counts, 0, NEXP * sizeof(int), stream);
  count_kernel<<<(T + 255) / 256, 256, 0, stream>>>(tok_ids, counts, T);
  scan_kernel<<<1, 64, 0, stream>>>(counts, offsets, cursors);
  scatter_kernel<<<(T + 255) / 256, 256, 0, stream>>>(tok_ids, cursors, tok_list, T);

  const size_t xp_bytes  = (size_t)T * HIDDEN * 2;          // 67.1 MB
  const size_t w_bytes   = (size_t)NEXP * HIDDEN * EINTER * 2;  // 33.5 MB each
  const size_t act_bf16  = (size_t)T * EINTER * 2;          // 33.5 MB
  const size_t need_bf16 = hdr_bytes + xp_bytes + 3 * w_bytes + act_bf16;

  if (ws_size >= need_bf16) {
    char* p = (char*)d_ws + hdr_bytes;
    u16* xp = (u16*)p;             p += xp_bytes;
    u16* Gt = (u16*)p;             p += w_bytes;
    u16* Ut = (u16*)p;             p += w_bytes;
    u16* Dt = (u16*)p;             p += w_bytes;
    u16* act = (u16*)p;

    gather_x_kernel<<<T, 256, 0, stream>>>(x, tok_list, xp);
    // G,U: [2048][1024] -> [1024][2048]; D: [1024][2048] -> [2048][1024]
    transpose_cvt_kernel<<<dim3(EINTER / 32, HIDDEN / 32, NEXP), 256, 0, stream>>>(G, Gt, HIDDEN, EINTER);
    transpose_cvt_kernel<<<dim3(EINTER / 32, HIDDEN / 32, NEXP), 256, 0, stream>>>(U, Ut, HIDDEN, EINTER);
    transpose_cvt_kernel<<<dim3(HIDDEN / 32, EINTER / 32, NEXP), 256, 0, stream>>>(D, Dt, EINTER, HIDDEN);

    dim3 g1(EINTER / 64, (T + 127) / 128, NEXP);
    gate_up_mfma<<<g1, 256, 0, stream>>>(xp, Gt, Ut, counts, offsets, act);
    dim3 g2(HIDDEN / 128, (T + 127) / 128, NEXP);
    down_mfma<<<g2, 256, 0, stream>>>(act, Dt, counts, offsets, tok_list, out);
  } else {
    float* act = (float*)((char*)d_ws + hdr_bytes);
    dim3 g1(EINTER / TN, (T + TM - 1) / TM, NEXP);
    gate_up_fp32<<<g1, 256, 0, stream>>>(x, G, U, counts, offsets, tok_list, act);
    dim3 g2(HIDDEN / TN, (T + TM - 1) / TM, NEXP);
    down_fp32<<<g2, 256, 0, stream>>>(act, D, counts, offsets, tok_list, out);
  }
}

// Round 3
// 740.413 us; speedup vs baseline: 4.1230x; 1.1555x over previous
//
#include <hip/hip_runtime.h>
#include <hip/hip_bf16.h>
#include <cstdint>
#include <cstddef>

#define HIDDEN   2048
#define EINTER   1024
#define NEXP     8
#define VOCAB_SZ 100000
#define TOK_PER_EXP (VOCAB_SZ / NEXP)   // 12500

typedef unsigned short u16;
typedef __attribute__((ext_vector_type(8))) short short8;   // 8 bf16 in 4 VGPRs
typedef __attribute__((ext_vector_type(4))) float floatx4;  // MFMA C/D

__device__ __forceinline__ int expert_of(int id) {
  id = id < 0 ? 0 : (id > VOCAB_SZ - 1 ? VOCAB_SZ - 1 : id);
  int e = id / TOK_PER_EXP;
  return e > NEXP - 1 ? NEXP - 1 : e;
}

// async global->LDS, 16B per lane. LDS dest = wave-uniform base + lane*16.
__device__ __forceinline__ void gl16(const u16* g, u16* l) {
  __builtin_amdgcn_global_load_lds(
      (const __attribute__((address_space(1))) uint32_t*)g,
      (__attribute__((address_space(3))) uint32_t*)l, 16, 0, 0);
}

// fragment read from XOR-swizzled LDS tile: row stride 64 u16 (128B), chunk = 16B unit.
// storage slot of logical chunk c in row r is c ^ (r & 7)  -> conflict-free b128 reads.
__device__ __forceinline__ short8 ldfrag(const u16* base, int row, int chunk) {
  return *(const short8*)(base + (row << 6) + (((chunk ^ (row & 7))) << 3));
}

// ---------------- routing ----------------
__global__ void count_kernel(const int* __restrict__ tok_ids, int* __restrict__ counts, int T) {
  int t = blockIdx.x * blockDim.x + threadIdx.x;
  if (t < T) atomicAdd(&counts[expert_of(tok_ids[t])], 1);
}

__global__ void scan_kernel(const int* __restrict__ counts, int* __restrict__ offsets,
                            int* __restrict__ cursors) {
  if (threadIdx.x == 0) {
    int s = 0;
    for (int e = 0; e < NEXP; ++e) { offsets[e] = s; cursors[e] = s; s += counts[e]; }
  }
}

__global__ void scatter_kernel(const int* __restrict__ tok_ids, int* __restrict__ cursors,
                               int* __restrict__ tok_list, int T) {
  int t = blockIdx.x * blockDim.x + threadIdx.x;
  if (t < T) {
    int e = expert_of(tok_ids[t]);
    int pos = atomicAdd(&cursors[e], 1);
    tok_list[pos] = t;
  }
}

// ---------------- bf16 pre-pass ----------------
__global__ void gather_x_kernel(const float* __restrict__ x, const int* __restrict__ tok_list,
                                u16* __restrict__ xp) {
  const int row = blockIdx.x;
  const int tok = tok_list[row];
  const float* src = x + (size_t)tok * HIDDEN;
  u16* dst = xp + (size_t)row * HIDDEN;
  const int k = threadIdx.x * 8;
  float4 a = *(const float4*)(src + k);
  float4 b = *(const float4*)(src + k + 4);
  union { uint4 u; u16 s[8]; } pk;
  const float f[8] = {a.x, a.y, a.z, a.w, b.x, b.y, b.z, b.w};
#pragma unroll
  for (int i = 0; i < 8; ++i) {
    __hip_bfloat16 h = __float2bfloat16(f[i]);
    pk.s[i] = *reinterpret_cast<u16*>(&h);
  }
  *(uint4*)(dst + k) = pk.u;
}

// fp32 [R][C] -> bf16 [C][R], 64x64 tiles, 256 thr. Dual-tensor: z<split -> (in0,out0,e=z),
// else (in1,out1,e=z-split). Coalesced float4 reads / uint4 writes.
__global__ void transpose_cvt64(const float* __restrict__ in0, u16* __restrict__ out0,
                                const float* __restrict__ in1, u16* __restrict__ out1,
                                int R, int C, int split) {
  __shared__ float ts[64][65];
  const int z = blockIdx.z;
  const bool first = (z < split) || (in1 == nullptr);
  const float* in = first ? in0 : in1;
  u16* outp = first ? out0 : out1;
  const int e = first ? z : z - split;
  const size_t bo = (size_t)e * R * C;
  const int c0 = blockIdx.x * 64, r0 = blockIdx.y * 64;
  const int lr = threadIdx.x >> 2, lq = threadIdx.x & 3;
#pragma unroll
  for (int j = 0; j < 4; ++j)
    *(float4*)&ts[lr][lq * 16 + j * 4] =
        *(const float4*)&in[bo + (size_t)(r0 + lr) * C + c0 + lq * 16 + j * 4];
  __syncthreads();
#pragma unroll
  for (int j = 0; j < 2; ++j) {
    union { uint4 u; u16 s[8]; } pk;
#pragma unroll
    for (int i = 0; i < 8; ++i) {
      __hip_bfloat16 h = __float2bfloat16(ts[lq * 16 + j * 8 + i][lr]);
      pk.s[i] = *reinterpret_cast<u16*>(&h);
    }
    *(uint4*)&outp[bo + (size_t)(c0 + lr) * R + r0 + lq * 16 + j * 8] = pk.u;
  }
}

// ---------------- gate/up MFMA GEMM + silu*mul -> act (bf16) ----------------
// tile 128(rows) x 64(cols per G,U), BK=64. grid (EINTER/64, ceil(T/128), NEXP), 256 thr.
__global__ __launch_bounds__(256, 2) void gate_up_mfma(
    const u16* __restrict__ xp, const u16* __restrict__ Gt, const u16* __restrict__ Ut,
    const int* __restrict__ counts, const int* __restrict__ offsets,
    u16* __restrict__ act) {
  __shared__ __align__(16) u16 As[128 * 64];
  __shared__ __align__(16) u16 Bg[64 * 64];
  __shared__ __align__(16) u16 Bu[64 * 64];

  const int e = blockIdx.z;
  const int cnt = counts[e];
  const int row0 = blockIdx.y * 128;
  if (row0 >= cnt) return;
  const int off = offsets[e];
  const int i0 = blockIdx.x * 64;

  const int tid  = threadIdx.x;
  const int lane = tid & 63;
  const int wave = tid >> 6;
  const int quad = lane >> 4;
  const int l16  = lane & 15;

  const int lrow   = lane >> 3;                 // row within 8-row batch
  const int lchunk = (lane & 7) ^ lrow;         // logical 16B chunk this lane fetches

  const int wrow = (wave & 1) * 64;             // wave tile 64 x 32
  const int wcol = (wave >> 1) * 32;

  // per-lane global src pointers (rows fixed across K)
  const u16* aptr[4];
#pragma unroll
  for (int it = 0; it < 4; ++it) {
    int r = ((wave + 4 * it) << 3) + lrow;
    int rg = row0 + r; rg = rg < cnt ? rg : cnt - 1;
    aptr[it] = xp + (size_t)(off + rg) * HIDDEN + (lchunk << 3);
  }
  const u16* gptr[2];
  const u16* uptr[2];
#pragma unroll
  for (int it = 0; it < 2; ++it) {
    int n = ((wave + 4 * it) << 3) + lrow;
    gptr[it] = Gt + ((size_t)e * EINTER + i0 + n) * HIDDEN + (lchunk << 3);
    uptr[it] = Ut + ((size_t)e * EINTER + i0 + n) * HIDDEN + (lchunk << 3);
  }

  floatx4 accg[4][2], accu[4][2];
#pragma unroll
  for (int mf = 0; mf < 4; ++mf)
#pragma unroll
    for (int nf = 0; nf < 2; ++nf) {
      floatx4 z = {0.f, 0.f, 0.f, 0.f};
      accg[mf][nf] = z; accu[mf][nf] = z;
    }

  for (int k0 = 0; k0 < HIDDEN; k0 += 64) {
#pragma unroll
    for (int it = 0; it < 4; ++it)
      gl16(aptr[it] + k0, &As[(wave + 4 * it) << 9]);
#pragma unroll
    for (int it = 0; it < 2; ++it) {
      gl16(gptr[it] + k0, &Bg[(wave + 4 * it) << 9]);
      gl16(uptr[it] + k0, &Bu[(wave + 4 * it) << 9]);
    }
    __syncthreads();   // drains vmcnt (global_load_lds) before LDS reads
#pragma unroll
    for (int s = 0; s < 2; ++s) {
      short8 af[4], bgf[2], buf2[2];
#pragma unroll
      for (int mf = 0; mf < 4; ++mf)
        af[mf] = ldfrag(As, wrow + mf * 16 + l16, s * 4 + quad);
#pragma unroll
      for (int nf = 0; nf < 2; ++nf) {
        bgf[nf]  = ldfrag(Bg, wcol + nf * 16 + l16, s * 4 + quad);
        buf2[nf] = ldfrag(Bu, wcol + nf * 16 + l16, s * 4 + quad);
      }
#pragma unroll
      for (int mf = 0; mf < 4; ++mf)
#pragma unroll
        for (int nf = 0; nf < 2; ++nf) {
          accg[mf][nf] = __builtin_amdgcn_mfma_f32_16x16x32_bf16(af[mf], bgf[nf],  accg[mf][nf], 0, 0, 0);
          accu[mf][nf] = __builtin_amdgcn_mfma_f32_16x16x32_bf16(af[mf], buf2[nf], accu[mf][nf], 0, 0, 0);
        }
    }
    __syncthreads();
  }

  // C/D layout: col = lane&15, row = quad*4 + reg
#pragma unroll
  for (int mf = 0; mf < 4; ++mf)
#pragma unroll
    for (int nf = 0; nf < 2; ++nf)
#pragma unroll
      for (int rg = 0; rg < 4; ++rg) {
        int r = wrow + mf * 16 + quad * 4 + rg;
        if (row0 + r < cnt) {
          float g = accg[mf][nf][rg];
          float u = accu[mf][nf][rg];
          float y = (g / (1.f + __expf(-g))) * u;
          __hip_bfloat16 h = __float2bfloat16(y);
          act[((size_t)(off + row0 + r)) * EINTER + i0 + wcol + nf * 16 + l16] =
              *reinterpret_cast<u16*>(&h);
        }
      }
}

// ---------------- down MFMA GEMM, scatter fp32 rows to out ----------------
// tile 128 x 128, BK=64. grid (HIDDEN/128, ceil(T/128), NEXP), 256 thr.
__global__ __launch_bounds__(256, 2) void down_mfma(
    const u16* __restrict__ act, const u16* __restrict__ Dt,
    const int* __restrict__ counts, const int* __restrict__ offsets,
    const int* __restrict__ tok_list, float* __restrict__ out) {
  __shared__ __align__(16) u16 As[128 * 64];
  __shared__ __align__(16) u16 Bs[128 * 64];
  __shared__ int toks[128];

  const int e = blockIdx.z;
  const int cnt = counts[e];
  const int row0 = blockIdx.y * 128;
  if (row0 >= cnt) return;
  const int off = offsets[e];
  const int j0 = blockIdx.x * 128;

  const int tid  = threadIdx.x;
  const int lane = tid & 63;
  const int wave = tid >> 6;
  const int quad = lane >> 4;
  const int l16  = lane & 15;

  const int lrow   = lane >> 3;
  const int lchunk = (lane & 7) ^ lrow;

  const int wrow = (wave & 1) * 64;   // wave tile 64 x 64
  const int wcol = (wave >> 1) * 64;

  if (tid < 128) {
    int r = row0 + tid;
    toks[tid] = tok_list[off + (r < cnt ? r : cnt - 1)];
  }

  const u16* aptr[4];
  const u16* dptr[4];
#pragma unroll
  for (int it = 0; it < 4; ++it) {
    int r = ((wave + 4 * it) << 3) + lrow;
    int rg = row0 + r; rg = rg < cnt ? rg : cnt - 1;
    aptr[it] = act + (size_t)(off + rg) * EINTER + (lchunk << 3);
    dptr[it] = Dt + ((size_t)e * HIDDEN + j0 + r) * EINTER + (lchunk << 3);
  }

  floatx4 acc[4][4];
#pragma unroll
  for (int mf = 0; mf < 4; ++mf)
#pragma unroll
    for (int nf = 0; nf < 4; ++nf) {
      floatx4 z = {0.f, 0.f, 0.f, 0.f};
      acc[mf][nf] = z;
    }

  for (int k0 = 0; k0 < EINTER; k0 += 64) {
#pragma unroll
    for (int it = 0; it < 4; ++it) {
      gl16(aptr[it] + k0, &As[(wave + 4 * it) << 9]);
      gl16(dptr[it] + k0, &Bs[(wave + 4 * it) << 9]);
    }
    __syncthreads();
#pragma unroll
    for (int s = 0; s < 2; ++s) {
      short8 af[4], bf[4];
#pragma unroll
      for (int mf = 0; mf < 4; ++mf)
        af[mf] = ldfrag(As, wrow + mf * 16 + l16, s * 4 + quad);
#pragma unroll
      for (int nf = 0; nf < 4; ++nf)
        bf[nf] = ldfrag(Bs, wcol + nf * 16 + l16, s * 4 + quad);
#pragma unroll
      for (int mf = 0; mf < 4; ++mf)
#pragma unroll
        for (int nf = 0; nf < 4; ++nf)
          acc[mf][nf] = __builtin_amdgcn_mfma_f32_16x16x32_bf16(af[mf], bf[nf], acc[mf][nf], 0, 0, 0);
    }
    __syncthreads();
  }

#pragma unroll
  for (int mf = 0; mf < 4; ++mf)
#pragma unroll
    for (int nf = 0; nf < 4; ++nf)
#pragma unroll
      for (int rg = 0; rg < 4; ++rg) {
        int r = wrow + mf * 16 + quad * 4 + rg;
        if (row0 + r < cnt)
          out[(size_t)toks[r] * HIDDEN + j0 + wcol + nf * 16 + l16] = acc[mf][nf][rg];
      }
}

// ---------------- fp32 fallback (round-1, known-correct; used only if ws too small) ----
#define TM 64
#define TN 64
#define TK 16

__global__ __launch_bounds__(256, 2) void gate_up_fp32(
    const float* __restrict__ x, const float* __restrict__ G, const float* __restrict__ U,
    const int* __restrict__ counts, const int* __restrict__ offsets,
    const int* __restrict__ tok_list, float* __restrict__ act) {
  __shared__ __align__(16) float Xs[TK][TM + 4];
  __shared__ __align__(16) float Gs[TK][TN];
  __shared__ __align__(16) float Us[TK][TN];
  __shared__ int toks[TM];
  const int e = blockIdx.z, cnt = counts[e], row0 = blockIdx.y * TM;
  if (row0 >= cnt) return;
  const int off = offsets[e], i0 = blockIdx.x * TN, tid = threadIdx.x;
  if (tid < TM) { int r = row0 + tid; toks[tid] = tok_list[off + (r < cnt ? r : 0)]; }
  __syncthreads();
  const float* Ge = G + (size_t)e * HIDDEN * EINTER + i0;
  const float* Ue = U + (size_t)e * HIDDEN * EINTER + i0;
  const int kk_ld = tid & 15, r_ld = tid >> 4, i_ld = tid & 63, k_ld = tid >> 6;
  const int tx = tid & 15, ty = tid >> 4;
  float ag[4][4] = {{0.f}}, au[4][4] = {{0.f}};
  for (int k0 = 0; k0 < HIDDEN; k0 += TK) {
#pragma unroll
    for (int rr = 0; rr < 4; ++rr) {
      int r = r_ld + rr * 16;
      Xs[kk_ld][r] = x[(size_t)toks[r] * HIDDEN + k0 + kk_ld];
    }
#pragma unroll
    for (int kk = 0; kk < 4; ++kk) {
      int k = k_ld + kk * 4;
      Gs[k][i_ld] = Ge[(size_t)(k0 + k) * EINTER + i_ld];
      Us[k][i_ld] = Ue[(size_t)(k0 + k) * EINTER + i_ld];
    }
    __syncthreads();
#pragma unroll
    for (int kk = 0; kk < TK; ++kk) {
      float4 a = *(const float4*)&Xs[kk][ty * 4];
      float4 bg = *(const float4*)&Gs[kk][tx * 4];
      float4 bu = *(const float4*)&Us[kk][tx * 4];
      const float av[4] = {a.x, a.y, a.z, a.w}, bgv[4] = {bg.x, bg.y, bg.z, bg.w},
                  buv[4] = {bu.x, bu.y, bu.z, bu.w};
#pragma unroll
      for (int i = 0; i < 4; ++i)
#pragma unroll
        for (int j = 0; j < 4; ++j) {
          ag[i][j] = fmaf(av[i], bgv[j], ag[i][j]);
          au[i][j] = fmaf(av[i], buv[j], au[i][j]);
        }
    }
    __syncthreads();
  }
#pragma unroll
  for (int i = 0; i < 4; ++i) {
    int r = row0 + ty * 4 + i;
    if (r < cnt) {
      float4 o; float* op = (float*)&o;
#pragma unroll
      for (int j = 0; j < 4; ++j) {
        float g = ag[i][j], u = au[i][j];
        op[j] = (g / (1.0f + expf(-g))) * u;
      }
      *(float4*)&act[(size_t)(off + r) * EINTER + i0 + tx * 4] = o;
    }
  }
}

__global__ __launch_bounds__(256, 2) void down_fp32(
    const float* __restrict__ act, const float* __restrict__ D,
    const int* __restrict__ counts, const int* __restrict__ offsets,
    const int* __restrict__ tok_list, float* __restrict__ out) {
  __shared__ __align__(16) float As[TK][TM + 4];
  __shared__ __align__(16) float Ds[TK][TN];
  __shared__ int toks[TM];
  const int e = blockIdx.z, cnt = counts[e], row0 = blockIdx.y * TM;
  if (row0 >= cnt) return;
  const int off = offsets[e], j0 = blockIdx.x * TN, tid = threadIdx.x;
  if (tid < TM) { int r = row0 + tid; toks[tid] = tok_list[off + (r < cnt ? r : 0)]; }
  const float* De = D + (size_t)e * EINTER * HIDDEN + j0;
  const int kk_ld = tid & 15, r_ld = tid >> 4, i_ld = tid & 63, k_ld = tid >> 6;
  const int tx = tid & 15, ty = tid >> 4;
  float acc[4][4] = {{0.f}};
  for (int k0 = 0; k0 < EINTER; k0 += TK) {
#pragma unroll
    for (int rr = 0; rr < 4; ++rr) {
      int r = r_ld + rr * 16;
      int grow = row0 + r;
      As[kk_ld][r] = act[(size_t)(off + (grow < cnt ? grow : 0)) * EINTER + k0 + kk_ld];
    }
#pragma unroll
    for (int kk = 0; kk < 4; ++kk) {
      int k = k_ld + kk * 4;
      Ds[k][i_ld] = De[(size_t)(k0 + k) * HIDDEN + i_ld];
    }
    __syncthreads();
#pragma unroll
    for (int kk = 0; kk < TK; ++kk) {
      float4 a = *(const float4*)&As[kk][ty * 4];
      float4 b = *(const float4*)&Ds[kk][tx * 4];
      const float av[4] = {a.x, a.y, a.z, a.w}, bv[4] = {b.x, b.y, b.z, b.w};
#pragma unroll
      for (int i = 0; i < 4; ++i)
#pragma unroll
        for (int j = 0; j < 4; ++j)
          acc[i][j] = fmaf(av[i], bv[j], acc[i][j]);
    }
    __syncthreads();
  }
#pragma unroll
  for (int i = 0; i < 4; ++i) {
    int r = row0 + ty * 4 + i;
    if (r < cnt) {
      float4 o = {acc[i][0], acc[i][1], acc[i][2], acc[i][3]};
      *(float4*)&out[(size_t)toks[ty * 4 + i] * HIDDEN + j0 + tx * 4] = o;
    }
  }
}

// ---------------- launch ----------------
extern "C" void kernel_launch(void* const* d_in, const int* in_sizes, int n_in,
                              void* d_out, int out_size, void* d_ws, size_t ws_size,
                              hipStream_t stream) {
  const float* x       = (const float*)d_in[0];
  const int*   tok_ids = (const int*)d_in[1];
  const float* G       = (const float*)d_in[2];
  const float* U       = (const float*)d_in[3];
  const float* D       = (const float*)d_in[4];
  float* out = (float*)d_out;

  const int T = in_sizes[0] / HIDDEN;  // 16384

  int* counts   = (int*)d_ws;
  int* offsets  = counts + NEXP;
  int* cursors  = offsets + NEXP;
  int* tok_list = cursors + NEXP;
  size_t hdr_bytes = (((size_t)(3 * NEXP + T) * sizeof(int)) + 255) & ~(size_t)255;

  hipMemsetAsync(counts, 0, NEXP * sizeof(int), stream);
  count_kernel<<<(T + 255) / 256, 256, 0, stream>>>(tok_ids, counts, T);
  scan_kernel<<<1, 64, 0, stream>>>(counts, offsets, cursors);
  scatter_kernel<<<(T + 255) / 256, 256, 0, stream>>>(tok_ids, cursors, tok_list, T);

  const size_t xp_bytes  = (size_t)T * HIDDEN * 2;
  const size_t w_bytes   = (size_t)NEXP * HIDDEN * EINTER * 2;
  const size_t act_bf16  = (size_t)T * EINTER * 2;
  const size_t need_bf16 = hdr_bytes + xp_bytes + 3 * w_bytes + act_bf16;

  if (ws_size >= need_bf16) {
    char* p = (char*)d_ws + hdr_bytes;
    u16* xp = (u16*)p;   p += xp_bytes;
    u16* Gt = (u16*)p;   p += w_bytes;
    u16* Ut = (u16*)p;   p += w_bytes;
    u16* Dt = (u16*)p;   p += w_bytes;
    u16* act = (u16*)p;

    gather_x_kernel<<<T, 256, 0, stream>>>(x, tok_list, xp);
    // G,U: [2048][1024] -> [1024][2048] (fused, z=16); D: [1024][2048] -> [2048][1024]
    transpose_cvt64<<<dim3(EINTER / 64, HIDDEN / 64, 2 * NEXP), 256, 0, stream>>>(
        G, Gt, U, Ut, HIDDEN, EINTER, NEXP);
    transpose_cvt64<<<dim3(HIDDEN / 64, EINTER / 64, NEXP), 256, 0, stream>>>(
        D, Dt, nullptr, nullptr, EINTER, HIDDEN, NEXP);

    dim3 g1(EINTER / 64, (T + 127) / 128, NEXP);
    gate_up_mfma<<<g1, 256, 0, stream>>>(xp, Gt, Ut, counts, offsets, act);
    dim3 g2(HIDDEN / 128, (T + 127) / 128, NEXP);
    down_mfma<<<g2, 256, 0, stream>>>(act, Dt, counts, offsets, tok_list, out);
  } else {
    float* act = (float*)((char*)d_ws + hdr_bytes);
    dim3 g1(EINTER / TN, (T + TM - 1) / TM, NEXP);
    gate_up_fp32<<<g1, 256, 0, stream>>>(x, G, U, counts, offsets, tok_list, act);
    dim3 g2(HIDDEN / TN, (T + TM - 1) / TM, NEXP);
    down_fp32<<<g2, 256, 0, stream>>>(act, D, counts, offsets, tok_list, out);
  }
}